// Round 1
// baseline (669.851 us; speedup 1.0000x reference)
//
#include <hip/hip_runtime.h>
#include <stdint.h>

// CGIterator on MI355X (gfx950).
// Layout convention: "stream" storage = concatenated per-l blocks, each (N, DEG_l, K)
// row-major. Element offset = l*l*NK + (n*(2l+1) + m_loc)*128 + k, with NK = N*K.
// This matches both the input feats and the concatenated tuple output.

#define N_ROWS 16384
#define NK (16384 * 128)        // elements per unit-degree stream block

typedef float f32x4 __attribute__((ext_vector_type(4)));
typedef short short8 __attribute__((ext_vector_type(8)));
typedef __bf16 bf16x8 __attribute__((ext_vector_type(8)));

__device__ __forceinline__ uint16_t f2b(float f) {   // f32 -> bf16 bits, RNE
  uint32_t u = __builtin_bit_cast(uint32_t, f);
  u += 0x7FFFu + ((u >> 16) & 1u);
  return (uint16_t)(u >> 16);
}
__device__ __forceinline__ float b2f(uint16_t h) {   // bf16 bits -> f32 (exact)
  uint32_t u = ((uint32_t)h) << 16;
  return __builtin_bit_cast(float, u);
}
__device__ __forceinline__ f32x4 mfma_bf16(short8 a, short8 b, f32x4 c) {
  return __builtin_amdgcn_mfma_f32_16x16x32_bf16(
      __builtin_bit_cast(bf16x8, a), __builtin_bit_cast(bf16x8, b), c, 0, 0, 0);
}

// row-tile index T in [0,16384) -> (l, row0 within stream l); 16-row tiles.
__device__ __forceinline__ void tile_decode(int T, int& l, int& row0) {
  l = (T >= 1024) + (T >= 4096) + (T >= 9216);
  row0 = (T - l * l * 1024) * 16;
}
// flattened m in [0,16) -> l and local m
__device__ __forceinline__ int l_of_m(int m) { return (m > 0) + (m > 3) + (m > 8); }

// ---------------------------------------------------------------------------
// K0: prep — bf16-transpose weights ([k][q] -> [q][k]) and build Ccat[16][256].
// ---------------------------------------------------------------------------
__global__ __launch_bounds__(256) void k0_prep(
    const float* __restrict__ mixw, const float* __restrict__ iterw,
    const float* __restrict__ cg,
    uint16_t* __restrict__ wtmix, uint16_t* __restrict__ wtiter,
    uint16_t* __restrict__ ccat) {
  int idx = blockIdx.x * 256 + threadIdx.x;
  const int NMIX = 3 * 4 * 16384, NITR = 2 * 4 * 16384;
  if (idx < NMIX) {
    int il = idx >> 14, rem = idx & 16383, q = rem >> 7, k = rem & 127;
    wtmix[idx] = f2b(mixw[il * 16384 + k * 128 + q]);
  } else if (idx < NMIX + NITR) {
    int o = idx - NMIX;
    int tl = o >> 14, rem = o & 16383, q = rem >> 7, k = rem & 127;
    wtiter[o] = f2b(iterw[tl * 16384 + k * 128 + q]);
  } else if (idx < NMIX + NITR + 4096) {
    int o = idx - NMIX - NITR;
    int mg = o >> 8, ij = o & 255, ig = ij >> 4, jg = ij & 15;
    int l = l_of_m(mg), m = mg - l * l;
    int l1 = l_of_m(ig), i = ig - l1 * l1;
    int l2 = l_of_m(jg), j = jg - l2 * l2;
    // cg[(l1,l2,l,i,j,m)], shape (4,4,4,7,7,7); invalid triples are 0 by mask.
    ccat[o] = f2b(cg[(l1 * 16 + l2 * 4 + l) * 343 + i * 49 + j * 7 + m]);
  }
}

// ---------------------------------------------------------------------------
// K1: mixing — mixed[i] = density @ mixer_w[i], i = 0..2.
// mixed[0] -> d_out (fp32, becomes `current`); mixed[1],[2] -> ws (bf16).
// One wave per 16-row tile of one l-stream; block = 4 waves = 4 tiles.
// ---------------------------------------------------------------------------
__global__ __launch_bounds__(256) void k1_mix(
    const float* __restrict__ f0, const float* __restrict__ f1,
    const float* __restrict__ f2, const float* __restrict__ f3,
    const uint16_t* __restrict__ wtmix,
    float* __restrict__ out0, uint16_t* __restrict__ m1,
    uint16_t* __restrict__ m2) {
  int lane = threadIdx.x & 63, wid = threadIdx.x >> 6;
  int g = lane >> 4, r = lane & 15;
  int T = blockIdx.x * 4 + wid;
  int l, row0; tile_decode(T, l, row0);
  const float* F = (l == 0) ? f0 : (l == 1) ? f1 : (l == 2) ? f2 : f3;

  // A-fragments: A[r][g*8+e] = F[row0+r][kk*32+g*8+e]  (fp32 -> bf16)
  short8 af[4];
#pragma unroll
  for (int kk = 0; kk < 4; ++kk) {
    const float* p = F + (size_t)(row0 + r) * 128 + kk * 32 + g * 8;
    f32x4 x = *(const f32x4*)p;
    f32x4 y = *(const f32x4*)(p + 4);
    short8 v;
#pragma unroll
    for (int e = 0; e < 4; ++e) { v[e] = (short)f2b(x[e]); v[4 + e] = (short)f2b(y[e]); }
    af[kk] = v;
  }
  size_t seg = (size_t)l * l * NK;
#pragma unroll
  for (int i = 0; i < 3; ++i) {
    const uint16_t* W = wtmix + (i * 4 + l) * 16384;   // [q][k] bf16
#pragma unroll
    for (int qt = 0; qt < 8; ++qt) {
      f32x4 acc = {0.f, 0.f, 0.f, 0.f};
#pragma unroll
      for (int kk = 0; kk < 4; ++kk) {
        short8 bfr = *(const short8*)(W + (qt * 16 + r) * 128 + kk * 32 + g * 8);
        acc = mfma_bf16(af[kk], bfr, acc);
      }
#pragma unroll
      for (int j = 0; j < 4; ++j) {
        size_t idx = seg + (size_t)(row0 + g * 4 + j) * 128 + qt * 16 + r;
        if (i == 0) out0[idx] = acc[j];
        else if (i == 1) m1[idx] = f2b(acc[j]);
        else m2[idx] = f2b(acc[j]);
      }
    }
  }
}

// ---------------------------------------------------------------------------
// K2a: tensor product — tp = Ccat(16x256) @ P(256x128) per row n.
// a = current (fp32, d_out), b = mixed[t+1] (bf16, ws). One wave per n.
// P chunks (32 ij x 128 k, bf16) built in wave-private LDS, XOR-swizzled.
// ---------------------------------------------------------------------------
__global__ __launch_bounds__(256) void k2a_tp(
    const float* __restrict__ cur, const uint16_t* __restrict__ mixedb,
    const uint16_t* __restrict__ ccat, uint16_t* __restrict__ tpo) {
  __shared__ __align__(16) uint16_t lds[4][2048 + 2048 + 4096]; // a_s,b_s,pt / wave
  int lane = threadIdx.x & 63, wid = threadIdx.x >> 6;
  int g = lane >> 4, r = lane & 15;
  int n = blockIdx.x * 4 + wid;
  uint16_t* a_s = lds[wid];
  uint16_t* b_s = a_s + 2048;
  uint16_t* pt  = b_s + 2048;   // [k][ij_loc] bf16, byte addr ^((k&3)<<4)

  // stage a (fp32->bf16) and b (bf16 copy), 16 rows x 128
#pragma unroll
  for (int m = 0; m < 16; ++m) {
    int l = l_of_m(m), loc = m - l * l;
    size_t base = (size_t)l * l * NK + ((size_t)n * (2 * l + 1) + loc) * 128;
    a_s[m * 128 + lane]      = f2b(cur[base + lane]);
    a_s[m * 128 + 64 + lane] = f2b(cur[base + 64 + lane]);
    ((unsigned int*)(b_s + m * 128))[lane] = ((const unsigned int*)(mixedb + base))[lane];
  }
  __syncthreads();

  // Ccat A-fragments: A[r][cc*32+g*8+e]
  short8 cf[8];
#pragma unroll
  for (int cc = 0; cc < 8; ++cc)
    cf[cc] = *(const short8*)(ccat + r * 256 + cc * 32 + g * 8);

  f32x4 acc[8];
#pragma unroll
  for (int kt = 0; kt < 8; ++kt) acc[kt] = f32x4{0.f, 0.f, 0.f, 0.f};

  const int jb = (g & 1) * 8;
#pragma unroll
  for (int cc = 0; cc < 8; ++cc) {
    int iG = cc * 2 + (g >> 1);
    // build P chunk: lane covers ij_loc = g*8+e, k = ki*16+r
#pragma unroll
    for (int ki = 0; ki < 8; ++ki) {
      int k = ki * 16 + r;
      float av = b2f(a_s[iG * 128 + k]);
      short8 pv;
#pragma unroll
      for (int e = 0; e < 8; ++e) {
        float bv = b2f(b_s[(jb + e) * 128 + k]);
        pv[e] = (short)f2b(av * bv);
      }
      *(short8*)((char*)pt + (((k * 64) + g * 16) ^ ((k & 3) << 4))) = pv;
    }
    __syncthreads();
    // consume: B[ij=cc*32+g*8+e][k=kt*16+r]
#pragma unroll
    for (int kt = 0; kt < 8; ++kt) {
      int k = kt * 16 + r;
      short8 pb = *(const short8*)((char*)pt + (((k * 64) + g * 16) ^ ((k & 3) << 4)));
      acc[kt] = mfma_bf16(cf[cc], pb, acc[kt]);
    }
    __syncthreads();  // protect pt before next chunk overwrites
  }

  // store tp (bf16, stream layout): D[m=g*4+j][k=kt*16+r]
#pragma unroll
  for (int kt = 0; kt < 8; ++kt) {
#pragma unroll
    for (int j = 0; j < 4; ++j) {
      int m = g * 4 + j;
      int l = l_of_m(m), loc = m - l * l;
      size_t idx = (size_t)l * l * NK + ((size_t)n * (2 * l + 1) + loc) * 128 + kt * 16 + r;
      tpo[idx] = f2b(acc[kt][j]);
    }
  }
}

// ---------------------------------------------------------------------------
// K2b: current += tp @ iter_w[t]  (per-l-stream GEMM + RMW epilogue)
// ---------------------------------------------------------------------------
__global__ __launch_bounds__(256) void k2b_lin(
    const uint16_t* __restrict__ tp, const uint16_t* __restrict__ wt,
    float* __restrict__ cur) {
  int lane = threadIdx.x & 63, wid = threadIdx.x >> 6;
  int g = lane >> 4, r = lane & 15;
  int T = blockIdx.x * 4 + wid;
  int l, row0; tile_decode(T, l, row0);
  size_t seg = (size_t)l * l * NK;

  short8 af[4];
#pragma unroll
  for (int kk = 0; kk < 4; ++kk)
    af[kk] = *(const short8*)(tp + seg + (size_t)(row0 + r) * 128 + kk * 32 + g * 8);

  const uint16_t* W = wt + l * 16384;   // [q][k] bf16
#pragma unroll
  for (int qt = 0; qt < 8; ++qt) {
    f32x4 acc = {0.f, 0.f, 0.f, 0.f};
#pragma unroll
    for (int kk = 0; kk < 4; ++kk) {
      short8 b = *(const short8*)(W + (qt * 16 + r) * 128 + kk * 32 + g * 8);
      acc = mfma_bf16(af[kk], b, acc);
    }
#pragma unroll
    for (int j = 0; j < 4; ++j) {
      size_t idx = seg + (size_t)(row0 + g * 4 + j) * 128 + qt * 16 + r;
      cur[idx] += acc[j];
    }
  }
}

// ---------------------------------------------------------------------------
extern "C" void kernel_launch(void* const* d_in, const int* in_sizes, int n_in,
                              void* d_out, int out_size, void* d_ws, size_t ws_size,
                              hipStream_t stream) {
  const float* f0    = (const float*)d_in[0];
  const float* f1    = (const float*)d_in[1];
  const float* f2    = (const float*)d_in[2];
  const float* f3    = (const float*)d_in[3];
  const float* mixw  = (const float*)d_in[4];
  const float* iterw = (const float*)d_in[5];
  const float* cg    = (const float*)d_in[6];
  float* out = (float*)d_out;

  // ws layout (uint16 elements): wtmix 196608 | wtiter 131072 | ccat 4096 |
  // mixed1 33554432 | mixed2 33554432 | tp 33554432   (~193 MB total)
  uint16_t* wtmix  = (uint16_t*)d_ws;
  uint16_t* wtiter = wtmix + 196608;
  uint16_t* ccat   = wtiter + 131072;
  uint16_t* m1     = ccat + 4096;
  uint16_t* m2     = m1 + 33554432;
  uint16_t* tpb    = m2 + 33554432;

  k0_prep<<<1296, 256, 0, stream>>>(mixw, iterw, cg, wtmix, wtiter, ccat);
  k1_mix<<<4096, 256, 0, stream>>>(f0, f1, f2, f3, wtmix, out, m1, m2);
  // t = 0
  k2a_tp<<<4096, 256, 0, stream>>>(out, m1, ccat, tpb);
  k2b_lin<<<4096, 256, 0, stream>>>(tpb, wtiter + 0 * 4 * 16384, out);
  // t = 1
  k2a_tp<<<4096, 256, 0, stream>>>(out, m2, ccat, tpb);
  k2b_lin<<<4096, 256, 0, stream>>>(tpb, wtiter + 1 * 4 * 16384, out);
}